// Round 7
// baseline (590.893 us; speedup 1.0000x reference)
//
#include <hip/hip_runtime.h>
#include <hip/hip_fp16.h>

#define Bv 64
#define Gv 4096
#define Cv 32
#define Sv 16
#define Lv 4
#define NSTEP 4
#define LOG2E 1.4426950408889634f
#define LN2   0.6931471805599453f
#define GAMMA 0.01f
#define RLOG2E_G 144.26950408889634f   // LOG2E / GAMMA

// raw HW transcendentals: v_exp_f32 / v_log_f32 (base-2). Safe here:
// exp2 args in [-144.3, ~0] (flushed-denormal result => term provably negligible),
// log2 args in [~1, 16+] (sum always contains the max term ~ 1).
#define EXP2R(x) __builtin_amdgcn_exp2f(x)
#define LOG2R(x) __builtin_amdgcn_logf(x)

struct __align__(8) h4 { __half2 lo, hi; };

// ROCm hip_fp16.h has no __hmax2 -> emit v_pk_max_f16 directly (gfx950 VOP3P)
__device__ __forceinline__ __half2 hmax2(__half2 a, __half2 b) {
    unsigned x = *(unsigned*)&a, y = *(unsigned*)&b, r;
    asm("v_pk_max_f16 %0, %1, %2" : "=v"(r) : "v"(x), "v"(y));
    return *(__half2*)&r;
}

__device__ __forceinline__ float wave_max(float v) {
#pragma unroll
    for (int off = 32; off > 0; off >>= 1)
        v = fmaxf(v, __shfl_xor(v, off, 64));
    return v;
}

// 256-thread block -> one atomicMax (values all >= 0, so int-bit compare == float compare)
__device__ __forceinline__ void block_atomic_max(float v, float* dst, float* smax) {
    v = wave_max(v);
    int lane = threadIdx.x & 63;
    int wid  = threadIdx.x >> 6;
    if (lane == 0) smax[wid] = v;
    __syncthreads();
    if (threadIdx.x == 0) {
        float m = fmaxf(fmaxf(smax[0], smax[1]), fmaxf(smax[2], smax[3]));
        atomicMax((int*)dst, __float_as_int(m));
    }
}

// x [B,G] -> Rt [G,B] f32 and Rth [G,B] fp16   (LDS-tiled transpose, 64 g per block)
__global__ __launch_bounds__(256) void k_transpose(const float* __restrict__ x,
                                                   float* __restrict__ Rt,
                                                   __half2* __restrict__ Rth2) {
    __shared__ float tile[64][65];
    int g0 = blockIdx.x * 64;
#pragma unroll
    for (int i = 0; i < 16; ++i) {
        int t = threadIdx.x + i * 256;
        int b = t >> 6, gi = t & 63;
        tile[gi][b] = x[b * Gv + g0 + gi];
    }
    __syncthreads();
#pragma unroll
    for (int i = 0; i < 16; ++i) {
        int t = threadIdx.x + i * 256;
        int gi = t >> 6, b = t & 63;
        Rt[(g0 + gi) * 64 + b] = tile[gi][b];
    }
#pragma unroll
    for (int i = 0; i < 8; ++i) {
        int t = threadIdx.x + i * 256;
        int gi = t >> 5, bp = t & 31;
        Rth2[(g0 + gi) * 32 + bp] =
            __floats2half2_rn(tile[gi][2 * bp], tile[gi][2 * bp + 1]);
    }
}

// Lane = (g_sub 0..3, bg 0..15). Each lane owns batches 4bg..4bg+3 of grounding
// g = g0 + g_sub. Pass 1: fp16 gathers (8B/lane) + packed products + packed max.
// Products are PINNED in VGPRs via empty asm so the compiler cannot
// rematerialize them by re-gathering in pass 2 (round-6 regression cause).
// Pass 2: one exp2 per element-step.
__global__ __launch_bounds__(256, 4) void k_clauses(const h4* __restrict__ Rth4,
                                                    const int4* __restrict__ I4,
                                                    h4* __restrict__ Csh4,
                                                    float* __restrict__ Mc) {
    __shared__ float smax[4];
    int lane = threadIdx.x & 63;
    int wid  = threadIdx.x >> 6;
    int bg   = lane & 15;
    int gsub = lane >> 4;
    int blk  = blockIdx.x;              // 8192 blocks
    int c    = blk >> 8;                // 256 blocks per clause
    int g    = ((blk & 255) << 4) + (wid << 2) + gsub;
    const int4* __restrict__ Ig = I4 + (size_t)(c * Gv + g) * Sv;

    __half2 z = __float2half2_rn(0.0f);
    unsigned plo[Sv], phi[Sv];
    __half2 mlo = z, mhi = z;           // products are >= 0
#pragma unroll
    for (int s = 0; s < Sv; ++s) {
        int4 ii = Ig[s];
        h4 a = Rth4[((size_t)(unsigned)ii.x << 4) + bg];
        h4 b = Rth4[((size_t)(unsigned)ii.y << 4) + bg];
        h4 e = Rth4[((size_t)(unsigned)ii.z << 4) + bg];
        h4 d = Rth4[((size_t)(unsigned)ii.w << 4) + bg];
        __half2 pl = __hmul2(__hmul2(a.lo, b.lo), __hmul2(e.lo, d.lo));
        __half2 ph = __hmul2(__hmul2(a.hi, b.hi), __hmul2(e.hi, d.hi));
        mlo = hmax2(mlo, pl);
        mhi = hmax2(mhi, ph);
        unsigned plu = *(unsigned*)&pl, phu = *(unsigned*)&ph;
        asm("" : "+v"(plu));            // forbid rematerialization: value must
        asm("" : "+v"(phu));            // stay in a VGPR until pass 2
        plo[s] = plu;
        phi[s] = phu;
    }

    float m0 = __low2float(mlo), m1 = __high2float(mlo);
    float m2 = __low2float(mhi), m3 = __high2float(mhi);
    float a0 = -m0 * RLOG2E_G, a1 = -m1 * RLOG2E_G;
    float a2 = -m2 * RLOG2E_G, a3 = -m3 * RLOG2E_G;
    float s0 = 0.f, s1 = 0.f, s2 = 0.f, s3 = 0.f;
#pragma unroll
    for (int s = 0; s < Sv; ++s) {
        __half2 pl = *(__half2*)&plo[s];
        __half2 ph = *(__half2*)&phi[s];
        s0 += EXP2R(fmaf(__low2float(pl),  RLOG2E_G, a0));
        s1 += EXP2R(fmaf(__high2float(pl), RLOG2E_G, a1));
        s2 += EXP2R(fmaf(__low2float(ph),  RLOG2E_G, a2));
        s3 += EXP2R(fmaf(__high2float(ph), RLOG2E_G, a3));
    }
    float l0 = fmaf(GAMMA * LN2, LOG2R(s0), m0);
    float l1 = fmaf(GAMMA * LN2, LOG2R(s1), m1);
    float l2 = fmaf(GAMMA * LN2, LOG2R(s2), m2);
    float l3 = fmaf(GAMMA * LN2, LOG2R(s3), m3);

    h4 outv;
    outv.lo = __floats2half2_rn(l0, l1);
    outv.hi = __floats2half2_rn(l2, l3);
    Csh4[((size_t)(c * Gv + g) << 4) + bg] = outv;

    float v = fmaxf(fmaxf(l0, l1), fmaxf(l2, l3));
    block_atomic_max(v, Mc + c, smax);      // c uniform across block
}

// coef[c] = softmax(W)[c] / max(Mc[c], 1)   -- 32 threads
__global__ __launch_bounds__(64) void k_coef(const float* __restrict__ W,
                                             const float* __restrict__ Mc,
                                             float* __restrict__ coef) {
    int c = threadIdx.x;
    float e = EXP2R(W[c] * LOG2E);
    float wsum = e;
#pragma unroll
    for (int off = 16; off > 0; off >>= 1)
        wsum += __shfl_xor(wsum, off, 64);
    coef[c] = e / (wsum * fmaxf(Mc[c], 1.0f));
}

// H[b,g] = sum_c coef[c] * Cs[c,b,g] ; track global max.  4 elements per thread.
__global__ __launch_bounds__(256) void k_combine(const h4* __restrict__ Csh4,
                                                 const float* __restrict__ coef,
                                                 float4* __restrict__ H4,
                                                 float* __restrict__ Hmax) {
    __shared__ float smax[4];
    int tid = blockIdx.x * 256 + threadIdx.x;     // 0 .. B*G/4-1
    float4 h = make_float4(0.f, 0.f, 0.f, 0.f);
#pragma unroll
    for (int c = 0; c < Cv; ++c) {
        float w = coef[c];                         // uniform -> scalar load
        h4 v = Csh4[(size_t)c * (Gv * 16) + tid];
        h.x = fmaf(w, __low2float(v.lo),  h.x);
        h.y = fmaf(w, __high2float(v.lo), h.y);
        h.z = fmaf(w, __low2float(v.hi),  h.z);
        h.w = fmaf(w, __high2float(v.hi), h.w);
    }
    H4[tid] = h;
    float v = fmaxf(fmaxf(h.x, h.y), fmaxf(h.z, h.w));
    block_atomic_max(v, Hmax, smax);
}

// ls = softor2(R, H/max(Hmax,1)) un-normalized ; track global max
__global__ __launch_bounds__(256) void k_update(const float* __restrict__ Rt,
                                                const float* __restrict__ H,
                                                const float* __restrict__ Hmax,
                                                float* __restrict__ Lraw,
                                                float* __restrict__ Lmax) {
    __shared__ float smax[4];
    int tid = blockIdx.x * 256 + threadIdx.x;
    float hden = fmaxf(Hmax[0], 1.0f);
    float hn = H[tid] / hden;
    float r  = Rt[tid];
    float mx = fmaxf(r, hn), mn = fminf(r, hn);
    float t  = EXP2R((mn - mx) * RLOG2E_G);
    float ls = fmaf(GAMMA * LN2, LOG2R(1.0f + t), mx);
    Lraw[tid] = ls;
    block_atomic_max(ls, Lmax, smax);
}

// R = Lraw / max(Lmax,1); non-last steps refresh Rt (f32) + Rth (fp16);
// last step writes output in [B,G] layout
__global__ __launch_bounds__(256) void k_norm(const float* __restrict__ Lraw,
                                              const float* __restrict__ Lmax,
                                              float* __restrict__ Rt,
                                              __half* __restrict__ Rth,
                                              float* __restrict__ out,
                                              int last) {
    int tid = blockIdx.x * 256 + threadIdx.x;
    float d = fmaxf(Lmax[0], 1.0f);
    float v = Lraw[tid] / d;
    if (last) {
        int g = tid >> 6, b = tid & 63;
        out[b * Gv + g] = v;
    } else {
        Rt[tid] = v;
        Rth[tid] = __float2half(v);
    }
}

extern "C" void kernel_launch(void* const* d_in, const int* in_sizes, int n_in,
                              void* d_out, int out_size, void* d_ws, size_t ws_size,
                              hipStream_t stream) {
    const float* x = (const float*)d_in[0];   // [64, 4096]
    const float* W = (const float*)d_in[1];   // [1, 32]
    const int*   I = (const int*)d_in[2];     // [32, 4096, 16, 4]
    float* out = (float*)d_out;               // [64, 4096]

    float*  ws   = (float*)d_ws;
    float*  Rt   = ws;                         // 262144 floats  [G,B] f32
    float*  H    = ws + 262144;                // 262144
    float*  Lraw = ws + 524288;                // 262144
    float*  maxb = ws + 786432;                // 4 * 128 floats (atomics + coef)
    __half* Rth  = (__half*)(ws + 786944);     // 262144 halves [G,B] fp16
    __half* Csh  = (__half*)(ws + 1048576);    // 8388608 halves (16 MB)

    (void)hipMemsetAsync(maxb, 0, NSTEP * 128 * sizeof(float), stream);
    k_transpose<<<Gv / 64, 256, 0, stream>>>(x, Rt, (__half2*)Rth);

    for (int step = 0; step < NSTEP; ++step) {
        float* Mc   = maxb + step * 128;  // [32] per-clause maxima
        float* Hm   = Mc + 32;
        float* Lm   = Mc + 33;
        float* coef = Mc + 64;            // [32]
        k_clauses<<<(Cv * Gv) / 16, 256, 0, stream>>>((const h4*)Rth, (const int4*)I,
                                                      (h4*)Csh, Mc);
        k_coef   <<<1, 32, 0, stream>>>(W, Mc, coef);
        k_combine<<<(Bv * Gv) / 1024, 256, 0, stream>>>((const h4*)Csh, coef,
                                                        (float4*)H, Hm);
        k_update <<<(Bv * Gv) / 256, 256, 0, stream>>>(Rt, H, Hm, Lraw, Lm);
        k_norm   <<<(Bv * Gv) / 256, 256, 0, stream>>>(Lraw, Lm, Rt, Rth, out,
                                                       step == NSTEP - 1);
    }
}

// Round 8
// 342.476 us; speedup vs baseline: 1.7254x; 1.7254x over previous
//
#include <hip/hip_runtime.h>
#include <hip/hip_fp16.h>

#define Bv 64
#define Gv 4096
#define Cv 32
#define Sv 16
#define Lv 4
#define NSTEP 4
#define LOG2E 1.4426950408889634f
#define LN2   0.6931471805599453f
#define GAMMA 0.01f
#define RLOG2E_G 144.26950408889634f   // LOG2E / GAMMA

// raw HW transcendentals: v_exp_f32 / v_log_f32 (base-2). Safe here:
// exp2 args in [-144.3, ~0] (flushed-denormal result => term provably negligible),
// log2 args in [~1, 16+] (sum always contains the max term ~ 1).
#define EXP2R(x) __builtin_amdgcn_exp2f(x)
#define LOG2R(x) __builtin_amdgcn_logf(x)

struct __align__(16) h8 { __half2 h[4]; };   // 8 fp16 values, one dwordx4
struct __align__(16) f8 { float4 a, b; };    // 8 f32 values

__device__ __forceinline__ float wave_max(float v) {
#pragma unroll
    for (int off = 32; off > 0; off >>= 1)
        v = fmaxf(v, __shfl_xor(v, off, 64));
    return v;
}

// 256-thread block -> one atomicMax (values all >= 0, int-bit compare == float compare)
__device__ __forceinline__ void block_atomic_max(float v, float* dst, float* smax) {
    v = wave_max(v);
    int lane = threadIdx.x & 63;
    int wid  = threadIdx.x >> 6;
    if (lane == 0) smax[wid] = v;
    __syncthreads();
    if (threadIdx.x == 0) {
        float m = fmaxf(fmaxf(smax[0], smax[1]), fmaxf(smax[2], smax[3]));
        atomicMax((int*)dst, __float_as_int(m));
    }
}

// x [B,G] -> Rt [G,B] f32 and Rth [G,B] fp16   (LDS-tiled transpose, 64 g per block)
__global__ __launch_bounds__(256) void k_transpose(const float* __restrict__ x,
                                                   float* __restrict__ Rt,
                                                   __half2* __restrict__ Rth2) {
    __shared__ float tile[64][65];
    int g0 = blockIdx.x * 64;
#pragma unroll
    for (int i = 0; i < 16; ++i) {
        int t = threadIdx.x + i * 256;
        int b = t >> 6, gi = t & 63;
        tile[gi][b] = x[b * Gv + g0 + gi];
    }
    __syncthreads();
#pragma unroll
    for (int i = 0; i < 16; ++i) {
        int t = threadIdx.x + i * 256;
        int gi = t >> 6, b = t & 63;
        Rt[(g0 + gi) * 64 + b] = tile[gi][b];
    }
#pragma unroll
    for (int i = 0; i < 8; ++i) {
        int t = threadIdx.x + i * 256;
        int gi = t >> 5, bp = t & 31;
        Rth2[(g0 + gi) * 32 + bp] =
            __floats2half2_rn(tile[gi][2 * bp], tile[gi][2 * bp + 1]);
    }
}

// Lane = (g_sub 0..7, bg 0..7). Each lane owns batches 8bg..8bg+7 (h8, 16B gather)
// of grounding g = g0 + g_sub. One wave covers 8 g; per s: 1 int4 idx load +
// 4 h8 gathers serve 8 g x 64 b. Online f32 LSE (no staging arrays -> no
// spill/remat traps). Products in packed fp16 (proven 2e-3 accurate, r6/7).
__global__ __launch_bounds__(256, 4) void k_clauses(const h8* __restrict__ Rth8,
                                                    const int4* __restrict__ I4,
                                                    h8* __restrict__ Csh8,
                                                    float* __restrict__ Mc) {
    __shared__ float smax[4];
    int lane = threadIdx.x & 63;
    int wid  = threadIdx.x >> 6;
    int bg   = lane & 7;
    int gsub = lane >> 3;
    int blk  = blockIdx.x;              // 4096 blocks
    int c    = blk >> 7;                // 128 blocks per clause
    int g    = ((blk & 127) << 5) + (wid << 3) + gsub;
    const int4* __restrict__ Ig = I4 + (size_t)(c * Gv + g) * Sv;

    float m[8], sum[8];
#pragma unroll
    for (int e = 0; e < 8; ++e) { m[e] = 0.0f; sum[e] = 0.0f; }

#pragma unroll
    for (int s = 0; s < Sv; ++s) {
        int4 ii = Ig[s];
        h8 A = Rth8[((size_t)(unsigned)ii.x << 3) + bg];
        h8 B = Rth8[((size_t)(unsigned)ii.y << 3) + bg];
        h8 E = Rth8[((size_t)(unsigned)ii.z << 3) + bg];
        h8 D = Rth8[((size_t)(unsigned)ii.w << 3) + bg];
#pragma unroll
        for (int j = 0; j < 4; ++j) {
            __half2 q = __hmul2(__hmul2(A.h[j], B.h[j]), __hmul2(E.h[j], D.h[j]));
            float p0 = __low2float(q), p1 = __high2float(q);
            int e0 = 2 * j, e1 = 2 * j + 1;
            float n0 = fmaxf(m[e0], p0);
            float n1 = fmaxf(m[e1], p1);
            sum[e0] = fmaf(sum[e0], EXP2R((m[e0] - n0) * RLOG2E_G),
                           EXP2R((p0 - n0) * RLOG2E_G));
            sum[e1] = fmaf(sum[e1], EXP2R((m[e1] - n1) * RLOG2E_G),
                           EXP2R((p1 - n1) * RLOG2E_G));
            m[e0] = n0;
            m[e1] = n1;
        }
    }

    float ls[8];
#pragma unroll
    for (int e = 0; e < 8; ++e)
        ls[e] = fmaf(GAMMA * LN2, LOG2R(sum[e]), m[e]);

    h8 outv;
#pragma unroll
    for (int j = 0; j < 4; ++j)
        outv.h[j] = __floats2half2_rn(ls[2 * j], ls[2 * j + 1]);
    Csh8[((size_t)(c * Gv + g) << 3) + bg] = outv;

    float v = ls[0];
#pragma unroll
    for (int e = 1; e < 8; ++e) v = fmaxf(v, ls[e]);
    block_atomic_max(v, Mc + c, smax);      // c uniform across block
}

// coef[c] = softmax(W)[c] / max(Mc[c], 1)   -- 32 threads
__global__ __launch_bounds__(64) void k_coef(const float* __restrict__ W,
                                             const float* __restrict__ Mc,
                                             float* __restrict__ coef) {
    int c = threadIdx.x;
    float e = EXP2R(W[c] * LOG2E);
    float wsum = e;
#pragma unroll
    for (int off = 16; off > 0; off >>= 1)
        wsum += __shfl_xor(wsum, off, 64);
    coef[c] = e / (wsum * fmaxf(Mc[c], 1.0f));
}

// H[b,g] = sum_c coef[c] * Cs[c,b,g] ; track global max.  8 elements per thread.
__global__ __launch_bounds__(256) void k_combine(const h8* __restrict__ Csh8,
                                                 const float* __restrict__ coef,
                                                 f8* __restrict__ H8,
                                                 float* __restrict__ Hmax) {
    __shared__ float smax[4];
    int tid = blockIdx.x * 256 + threadIdx.x;     // 0 .. B*G/8-1
    float h[8];
#pragma unroll
    for (int e = 0; e < 8; ++e) h[e] = 0.0f;
#pragma unroll
    for (int c = 0; c < Cv; ++c) {
        float w = coef[c];                         // uniform -> scalar load
        h8 v = Csh8[(size_t)c * (Gv * 8) + tid];
#pragma unroll
        for (int j = 0; j < 4; ++j) {
            h[2 * j]     = fmaf(w, __low2float(v.h[j]),  h[2 * j]);
            h[2 * j + 1] = fmaf(w, __high2float(v.h[j]), h[2 * j + 1]);
        }
    }
    f8 outv;
    outv.a = make_float4(h[0], h[1], h[2], h[3]);
    outv.b = make_float4(h[4], h[5], h[6], h[7]);
    H8[tid] = outv;
    float v = h[0];
#pragma unroll
    for (int e = 1; e < 8; ++e) v = fmaxf(v, h[e]);
    block_atomic_max(v, Hmax, smax);
}

// ls = softor2(R, H/max(Hmax,1)) un-normalized ; track global max
__global__ __launch_bounds__(256) void k_update(const float* __restrict__ Rt,
                                                const float* __restrict__ H,
                                                const float* __restrict__ Hmax,
                                                float* __restrict__ Lraw,
                                                float* __restrict__ Lmax) {
    __shared__ float smax[4];
    int tid = blockIdx.x * 256 + threadIdx.x;
    float hden = fmaxf(Hmax[0], 1.0f);
    float hn = H[tid] / hden;
    float r  = Rt[tid];
    float mx = fmaxf(r, hn), mn = fminf(r, hn);
    float t  = EXP2R((mn - mx) * RLOG2E_G);
    float ls = fmaf(GAMMA * LN2, LOG2R(1.0f + t), mx);
    Lraw[tid] = ls;
    block_atomic_max(ls, Lmax, smax);
}

// R = Lraw / max(Lmax,1); non-last steps refresh Rt (f32) + Rth (fp16);
// last step writes output in [B,G] layout
__global__ __launch_bounds__(256) void k_norm(const float* __restrict__ Lraw,
                                              const float* __restrict__ Lmax,
                                              float* __restrict__ Rt,
                                              __half* __restrict__ Rth,
                                              float* __restrict__ out,
                                              int last) {
    int tid = blockIdx.x * 256 + threadIdx.x;
    float d = fmaxf(Lmax[0], 1.0f);
    float v = Lraw[tid] / d;
    if (last) {
        int g = tid >> 6, b = tid & 63;
        out[b * Gv + g] = v;
    } else {
        Rt[tid] = v;
        Rth[tid] = __float2half(v);
    }
}

extern "C" void kernel_launch(void* const* d_in, const int* in_sizes, int n_in,
                              void* d_out, int out_size, void* d_ws, size_t ws_size,
                              hipStream_t stream) {
    const float* x = (const float*)d_in[0];   // [64, 4096]
    const float* W = (const float*)d_in[1];   // [1, 32]
    const int*   I = (const int*)d_in[2];     // [32, 4096, 16, 4]
    float* out = (float*)d_out;               // [64, 4096]

    float*  ws   = (float*)d_ws;
    float*  Rt   = ws;                         // 262144 floats  [G,B] f32
    float*  H    = ws + 262144;                // 262144
    float*  Lraw = ws + 524288;                // 262144
    float*  maxb = ws + 786432;                // 4 * 128 floats (atomics + coef)
    __half* Rth  = (__half*)(ws + 786944);     // 262144 halves [G,B] fp16
    __half* Csh  = (__half*)(ws + 1048576);    // 8388608 halves (16 MB)

    (void)hipMemsetAsync(maxb, 0, NSTEP * 128 * sizeof(float), stream);
    k_transpose<<<Gv / 64, 256, 0, stream>>>(x, Rt, (__half2*)Rth);

    for (int step = 0; step < NSTEP; ++step) {
        float* Mc   = maxb + step * 128;  // [32] per-clause maxima
        float* Hm   = Mc + 32;
        float* Lm   = Mc + 33;
        float* coef = Mc + 64;            // [32]
        k_clauses<<<(Cv * Gv) / 32, 256, 0, stream>>>((const h8*)Rth, (const int4*)I,
                                                      (h8*)Csh, Mc);
        k_coef   <<<1, 32, 0, stream>>>(W, Mc, coef);
        k_combine<<<(Bv * Gv) / 2048, 256, 0, stream>>>((const h8*)Csh, coef,
                                                        (f8*)H, Hm);
        k_update <<<(Bv * Gv) / 256, 256, 0, stream>>>(Rt, H, Hm, Lraw, Lm);
        k_norm   <<<(Bv * Gv) / 256, 256, 0, stream>>>(Lraw, Lm, Rt, Rth, out,
                                                       step == NSTEP - 1);
    }
}

// Round 9
// 296.620 us; speedup vs baseline: 1.9921x; 1.1546x over previous
//
#include <hip/hip_runtime.h>
#include <hip/hip_fp16.h>

#define Bv 64
#define Gv 4096
#define Cv 32
#define Sv 16
#define Lv 4
#define NSTEP 4
#define LOG2E 1.4426950408889634f
#define LN2   0.6931471805599453f
#define GAMMA 0.01f
#define RLOG2E_G 144.26950408889634f   // LOG2E / GAMMA

// raw HW transcendentals: v_exp_f32 / v_log_f32 (base-2). Safe here:
// exp2 args <= 0 (n is the group max), flushed-denormal terms provably negligible;
// log2 arg >= 1 (sum always contains the max term = 1).
#define EXP2R(x) __builtin_amdgcn_exp2f(x)
#define LOG2R(x) __builtin_amdgcn_logf(x)

struct __align__(16) h8 { __half2 h[4]; };   // 8 fp16 values, one dwordx4
struct __align__(16) f8 { float4 a, b; };    // 8 f32 values

__device__ __forceinline__ float wave_max(float v) {
#pragma unroll
    for (int off = 32; off > 0; off >>= 1)
        v = fmaxf(v, __shfl_xor(v, off, 64));
    return v;
}

// 256-thread block -> one atomicMax (values all >= 0, int-bit compare == float compare)
__device__ __forceinline__ void block_atomic_max(float v, float* dst, float* smax) {
    v = wave_max(v);
    int lane = threadIdx.x & 63;
    int wid  = threadIdx.x >> 6;
    if (lane == 0) smax[wid] = v;
    __syncthreads();
    if (threadIdx.x == 0) {
        float m = fmaxf(fmaxf(smax[0], smax[1]), fmaxf(smax[2], smax[3]));
        atomicMax((int*)dst, __float_as_int(m));
    }
}

// x [B,G] -> Rt [G,B] f32 and Rth [G,B] fp16   (LDS-tiled transpose, 64 g per block)
__global__ __launch_bounds__(256) void k_transpose(const float* __restrict__ x,
                                                   float* __restrict__ Rt,
                                                   __half2* __restrict__ Rth2) {
    __shared__ float tile[64][65];
    int g0 = blockIdx.x * 64;
#pragma unroll
    for (int i = 0; i < 16; ++i) {
        int t = threadIdx.x + i * 256;
        int b = t >> 6, gi = t & 63;
        tile[gi][b] = x[b * Gv + g0 + gi];
    }
    __syncthreads();
#pragma unroll
    for (int i = 0; i < 16; ++i) {
        int t = threadIdx.x + i * 256;
        int gi = t >> 6, b = t & 63;
        Rt[(g0 + gi) * 64 + b] = tile[gi][b];
    }
#pragma unroll
    for (int i = 0; i < 8; ++i) {
        int t = threadIdx.x + i * 256;
        int gi = t >> 5, bp = t & 31;
        Rth2[(g0 + gi) * 32 + bp] =
            __floats2half2_rn(tile[gi][2 * bp], tile[gi][2 * bp + 1]);
    }
}

// Lane = (g_sub 0..7, bg 0..7). Each lane owns batches 8bg..8bg+7 (h8, 16B gather)
// of grounding g. Amortized-group LSE: per 4 substitutions, one group max
// (v_max3-able chain) + ONE rescale exp2 -> 1.25 exp2/element instead of 2.
// p[4][8] lives only inside one sg-iteration (no pass boundary -> no remat).
// waves_per_eu(4,4) pins the allocator's occupancy target (r6/7: it chose
// 28 VGPRs and rematerialized gathers when left free).
__global__ __attribute__((amdgpu_flat_work_group_size(256, 256),
                          amdgpu_waves_per_eu(4, 4)))
void k_clauses(const h8* __restrict__ Rth8, const int4* __restrict__ I4,
               h8* __restrict__ Csh8, float* __restrict__ Mc) {
    __shared__ float smax[4];
    int lane = threadIdx.x & 63;
    int wid  = threadIdx.x >> 6;
    int bg   = lane & 7;
    int gsub = lane >> 3;
    int blk  = blockIdx.x;              // 4096 blocks
    int c    = blk >> 7;                // 128 blocks per clause
    int g    = ((blk & 127) << 5) + (wid << 3) + gsub;
    const int4* __restrict__ Ig = I4 + (size_t)(c * Gv + g) * Sv;

    float m[8], sum[8];
#pragma unroll
    for (int e = 0; e < 8; ++e) { m[e] = 0.0f; sum[e] = 0.0f; }

#pragma unroll
    for (int sg = 0; sg < Sv / 4; ++sg) {
        float p[4][8];
#pragma unroll
        for (int ss = 0; ss < 4; ++ss) {
            int4 ii = Ig[sg * 4 + ss];
            h8 A = Rth8[((size_t)(unsigned)ii.x << 3) + bg];
            h8 B = Rth8[((size_t)(unsigned)ii.y << 3) + bg];
            h8 E = Rth8[((size_t)(unsigned)ii.z << 3) + bg];
            h8 D = Rth8[((size_t)(unsigned)ii.w << 3) + bg];
#pragma unroll
            for (int j = 0; j < 4; ++j) {
                __half2 q = __hmul2(__hmul2(A.h[j], B.h[j]), __hmul2(E.h[j], D.h[j]));
                p[ss][2 * j]     = __low2float(q);
                p[ss][2 * j + 1] = __high2float(q);
            }
        }
#pragma unroll
        for (int e = 0; e < 8; ++e) {
            float n = fmaxf(m[e], fmaxf(fmaxf(p[0][e], p[1][e]),
                                        fmaxf(p[2][e], p[3][e])));
            float nk = n * RLOG2E_G;
            float t0 = EXP2R(fmaf(p[0][e], RLOG2E_G, -nk));
            float t1 = EXP2R(fmaf(p[1][e], RLOG2E_G, -nk));
            float t2 = EXP2R(fmaf(p[2][e], RLOG2E_G, -nk));
            float t3 = EXP2R(fmaf(p[3][e], RLOG2E_G, -nk));
            sum[e] = fmaf(sum[e], EXP2R(fmaf(m[e], RLOG2E_G, -nk)),
                          (t0 + t1) + (t2 + t3));
            m[e] = n;
        }
    }

    float ls[8];
#pragma unroll
    for (int e = 0; e < 8; ++e)
        ls[e] = fmaf(GAMMA * LN2, LOG2R(sum[e]), m[e]);

    h8 outv;
#pragma unroll
    for (int j = 0; j < 4; ++j)
        outv.h[j] = __floats2half2_rn(ls[2 * j], ls[2 * j + 1]);
    Csh8[((size_t)(c * Gv + g) << 3) + bg] = outv;

    float v = ls[0];
#pragma unroll
    for (int e = 1; e < 8; ++e) v = fmaxf(v, ls[e]);
    block_atomic_max(v, Mc + c, smax);      // c uniform across block
}

// H[b,g] = sum_c coef[c] * Cs[c,b,g], coef computed in-block (no k_coef launch);
// track global max.  8 elements per thread.
__global__ __launch_bounds__(256) void k_combine(const h8* __restrict__ Csh8,
                                                 const float* __restrict__ W,
                                                 const float* __restrict__ Mc,
                                                 f8* __restrict__ H8,
                                                 float* __restrict__ Hmax) {
    __shared__ float smax[4];
    __shared__ float scoef[Cv];
    if (threadIdx.x < Cv) {               // lanes 0..31 of wave 0
        int c = threadIdx.x;
        float e = EXP2R(W[c] * LOG2E);
        float wsum = e;
#pragma unroll
        for (int off = 16; off > 0; off >>= 1)
            wsum += __shfl_xor(wsum, off, 64);   // stays within lanes 0..31
        scoef[c] = e / (wsum * fmaxf(Mc[c], 1.0f));
    }
    __syncthreads();

    int tid = blockIdx.x * 256 + threadIdx.x;     // 0 .. B*G/8-1
    float h[8];
#pragma unroll
    for (int e = 0; e < 8; ++e) h[e] = 0.0f;
#pragma unroll
    for (int c = 0; c < Cv; ++c) {
        float w = scoef[c];                        // LDS broadcast
        h8 v = Csh8[(size_t)c * (Gv * 8) + tid];
#pragma unroll
        for (int j = 0; j < 4; ++j) {
            h[2 * j]     = fmaf(w, __low2float(v.h[j]),  h[2 * j]);
            h[2 * j + 1] = fmaf(w, __high2float(v.h[j]), h[2 * j + 1]);
        }
    }
    f8 outv;
    outv.a = make_float4(h[0], h[1], h[2], h[3]);
    outv.b = make_float4(h[4], h[5], h[6], h[7]);
    H8[tid] = outv;
    float v = h[0];
#pragma unroll
    for (int e = 1; e < 8; ++e) v = fmaxf(v, h[e]);
    block_atomic_max(v, Hmax, smax);
}

// ls = softor2(R, H/max(Hmax,1)) un-normalized ; track global max.  float4.
__global__ __launch_bounds__(256) void k_update(const float4* __restrict__ Rt4,
                                                const float4* __restrict__ H4,
                                                const float* __restrict__ Hmax,
                                                float4* __restrict__ Lraw4,
                                                float* __restrict__ Lmax) {
    __shared__ float smax[4];
    int tid = blockIdx.x * 256 + threadIdx.x;     // 0 .. B*G/4-1
    float hden = fmaxf(Hmax[0], 1.0f);
    float4 hv = H4[tid];
    float4 rv = Rt4[tid];
    float4 ls;
#pragma unroll
    for (int e = 0; e < 4; ++e) {
        float hn = (&hv.x)[e] / hden;
        float r  = (&rv.x)[e];
        float mx = fmaxf(r, hn), mn = fminf(r, hn);
        float t  = EXP2R((mn - mx) * RLOG2E_G);
        (&ls.x)[e] = fmaf(GAMMA * LN2, LOG2R(1.0f + t), mx);
    }
    Lraw4[tid] = ls;
    float v = fmaxf(fmaxf(ls.x, ls.y), fmaxf(ls.z, ls.w));
    block_atomic_max(v, Lmax, smax);
}

// R = Lraw / max(Lmax,1); non-last steps refresh Rt (f32) + Rth (fp16);
// last step writes output in [B,G] layout.  float4 (4 elems share one g).
__global__ __launch_bounds__(256) void k_norm(const float4* __restrict__ Lraw4,
                                              const float* __restrict__ Lmax,
                                              float4* __restrict__ Rt4,
                                              __half2* __restrict__ Rth2,
                                              float* __restrict__ out,
                                              int last) {
    int tid = blockIdx.x * 256 + threadIdx.x;     // 0 .. B*G/4-1
    float d = fmaxf(Lmax[0], 1.0f);
    float4 lv = Lraw4[tid];
    float4 v;
    v.x = lv.x / d; v.y = lv.y / d; v.z = lv.z / d; v.w = lv.w / d;
    if (last) {
        int lin = tid * 4;
        int g = lin >> 6, b = lin & 63;           // 4 consecutive b, same g
        out[(b + 0) * Gv + g] = v.x;
        out[(b + 1) * Gv + g] = v.y;
        out[(b + 2) * Gv + g] = v.z;
        out[(b + 3) * Gv + g] = v.w;
    } else {
        Rt4[tid] = v;
        Rth2[2 * tid]     = __floats2half2_rn(v.x, v.y);
        Rth2[2 * tid + 1] = __floats2half2_rn(v.z, v.w);
    }
}

extern "C" void kernel_launch(void* const* d_in, const int* in_sizes, int n_in,
                              void* d_out, int out_size, void* d_ws, size_t ws_size,
                              hipStream_t stream) {
    const float* x = (const float*)d_in[0];   // [64, 4096]
    const float* W = (const float*)d_in[1];   // [1, 32]
    const int*   I = (const int*)d_in[2];     // [32, 4096, 16, 4]
    float* out = (float*)d_out;               // [64, 4096]

    float*  ws   = (float*)d_ws;
    float*  Rt   = ws;                         // 262144 floats  [G,B] f32
    float*  H    = ws + 262144;                // 262144
    float*  Lraw = ws + 524288;                // 262144
    float*  maxb = ws + 786432;                // 4 * 64 floats (atomic slots)
    __half* Rth  = (__half*)(ws + 786944);     // 262144 halves [G,B] fp16
    __half* Csh  = (__half*)(ws + 1048576);    // 8388608 halves (16 MB)

    (void)hipMemsetAsync(maxb, 0, NSTEP * 64 * sizeof(float), stream);
    k_transpose<<<Gv / 64, 256, 0, stream>>>(x, Rt, (__half2*)Rth);

    for (int step = 0; step < NSTEP; ++step) {
        float* Mc = maxb + step * 64;     // [32] per-clause maxima
        float* Hm = Mc + 32;
        float* Lm = Mc + 33;
        k_clauses<<<(Cv * Gv) / 32, 256, 0, stream>>>((const h8*)Rth, (const int4*)I,
                                                      (h8*)Csh, Mc);
        k_combine<<<(Bv * Gv) / 2048, 256, 0, stream>>>((const h8*)Csh, W, Mc,
                                                        (f8*)H, Hm);
        k_update <<<(Bv * Gv) / 1024, 256, 0, stream>>>((const float4*)Rt,
                                                        (const float4*)H, Hm,
                                                        (float4*)Lraw, Lm);
        k_norm   <<<(Bv * Gv) / 1024, 256, 0, stream>>>((const float4*)Lraw, Lm,
                                                        (float4*)Rt, (__half2*)Rth,
                                                        out, step == NSTEP - 1);
    }
}

// Round 10
// 269.850 us; speedup vs baseline: 2.1897x; 1.0992x over previous
//
#include <hip/hip_runtime.h>
#include <hip/hip_fp16.h>

#define Bv 64
#define Gv 4096
#define Cv 32
#define Sv 16
#define Lv 4
#define NSTEP 4
#define LOG2E 1.4426950408889634f
#define LN2   0.6931471805599453f
#define GAMMA 0.01f
#define RLOG2E_G 144.26950408889634f        // LOG2E / GAMMA
#define SHIFT    72.0f                       // fixed LSE shift (see k_clauses)
#define UNSHIFT  0.4990659758388636f         // GAMMA * LN2 * 72

// raw HW transcendentals: v_exp_f32 / v_log_f32 (base-2). Safe here:
// exp2 arg in [-72, 72.3] (p in [0,1]) -> no overflow/underflow at all;
// log2 arg >= 16*2^-72 > 0.
#define EXP2R(x) __builtin_amdgcn_exp2f(x)
#define LOG2R(x) __builtin_amdgcn_logf(x)

struct __align__(16) h8 { __half2 h[4]; };   // 8 fp16 values, one dwordx4
struct __align__(16) f8 { float4 a, b; };    // 8 f32 values

__device__ __forceinline__ float wave_max(float v) {
#pragma unroll
    for (int off = 32; off > 0; off >>= 1)
        v = fmaxf(v, __shfl_xor(v, off, 64));
    return v;
}

// 256-thread block -> one atomicMax (values all >= 0, int-bit compare == float compare)
__device__ __forceinline__ void block_atomic_max(float v, float* dst, float* smax) {
    v = wave_max(v);
    int lane = threadIdx.x & 63;
    int wid  = threadIdx.x >> 6;
    if (lane == 0) smax[wid] = v;
    __syncthreads();
    if (threadIdx.x == 0) {
        float m = fmaxf(fmaxf(smax[0], smax[1]), fmaxf(smax[2], smax[3]));
        atomicMax((int*)dst, __float_as_int(m));
    }
}

// x [B,G] -> Rt [G,B] f32 and Rth [G,B] fp16   (LDS-tiled transpose, 64 g per block)
__global__ __launch_bounds__(256) void k_transpose(const float* __restrict__ x,
                                                   float* __restrict__ Rt,
                                                   __half2* __restrict__ Rth2) {
    __shared__ float tile[64][65];
    int g0 = blockIdx.x * 64;
#pragma unroll
    for (int i = 0; i < 16; ++i) {
        int t = threadIdx.x + i * 256;
        int b = t >> 6, gi = t & 63;
        tile[gi][b] = x[b * Gv + g0 + gi];
    }
    __syncthreads();
#pragma unroll
    for (int i = 0; i < 16; ++i) {
        int t = threadIdx.x + i * 256;
        int gi = t >> 6, b = t & 63;
        Rt[(g0 + gi) * 64 + b] = tile[gi][b];
    }
#pragma unroll
    for (int i = 0; i < 8; ++i) {
        int t = threadIdx.x + i * 256;
        int gi = t >> 5, bp = t & 31;
        Rth2[(g0 + gi) * 32 + bp] =
            __floats2half2_rn(tile[gi][2 * bp], tile[gi][2 * bp + 1]);
    }
}

// Lane = (g_sub 0..7, bg 0..7). Each lane owns batches 8bg..8bg+7 (h8, 16B gather).
// SHIFTED LSE: products p in [0,1] -> exp2(p*144.27 - 72) spans 2^+-72, no
// overflow/underflow possible -> NO running max, NO rescale. ls =
// gamma*ln2*log2(sum) + gamma*ln2*72. 8 independent sum chains -> max ILP.
__global__ __attribute__((amdgpu_flat_work_group_size(256, 256),
                          amdgpu_waves_per_eu(6, 6)))
void k_clauses(const h8* __restrict__ Rth8, const int4* __restrict__ I4,
               h8* __restrict__ Csh8, float* __restrict__ Mc) {
    __shared__ float smax[4];
    int lane = threadIdx.x & 63;
    int wid  = threadIdx.x >> 6;
    int bg   = lane & 7;
    int gsub = lane >> 3;
    int blk  = blockIdx.x;              // 4096 blocks
    int c    = blk >> 7;                // 128 blocks per clause
    int g    = ((blk & 127) << 5) + (wid << 3) + gsub;
    const int4* __restrict__ Ig = I4 + (size_t)(c * Gv + g) * Sv;

    float sum[8];
#pragma unroll
    for (int e = 0; e < 8; ++e) sum[e] = 0.0f;

#pragma unroll
    for (int s = 0; s < Sv; ++s) {
        int4 ii = Ig[s];
        h8 A = Rth8[((size_t)(unsigned)ii.x << 3) + bg];
        h8 B = Rth8[((size_t)(unsigned)ii.y << 3) + bg];
        h8 E = Rth8[((size_t)(unsigned)ii.z << 3) + bg];
        h8 D = Rth8[((size_t)(unsigned)ii.w << 3) + bg];
#pragma unroll
        for (int j = 0; j < 4; ++j) {
            __half2 q = __hmul2(__hmul2(A.h[j], B.h[j]), __hmul2(E.h[j], D.h[j]));
            sum[2 * j]     += EXP2R(fmaf(__low2float(q),  RLOG2E_G, -SHIFT));
            sum[2 * j + 1] += EXP2R(fmaf(__high2float(q), RLOG2E_G, -SHIFT));
        }
    }

    float ls[8];
#pragma unroll
    for (int e = 0; e < 8; ++e)
        ls[e] = fmaf(GAMMA * LN2, LOG2R(sum[e]), UNSHIFT);

    h8 outv;
#pragma unroll
    for (int j = 0; j < 4; ++j)
        outv.h[j] = __floats2half2_rn(ls[2 * j], ls[2 * j + 1]);
    Csh8[((size_t)(c * Gv + g) << 3) + bg] = outv;

    float v = ls[0];
#pragma unroll
    for (int e = 1; e < 8; ++e) v = fmaxf(v, ls[e]);
    block_atomic_max(v, Mc + c, smax);      // c uniform across block
}

// Fused combine+update. H = sum_c coef[c]*Cs_norm is a CONVEX combination of
// values <= 1 (Cs_norm = ls/max(Mc,1) <= 1 by construction), so the reference's
// max(Hmax,1) == 1 (+O(fp16 ulp)); we use hden = 1 exactly.
// ls = softor2(R, H) un-normalized; track global Lmax.  8 elems per thread.
__global__ __launch_bounds__(256) void k_combupd(const h8* __restrict__ Csh8,
                                                 const float* __restrict__ W,
                                                 const float* __restrict__ Mc,
                                                 const f8* __restrict__ Rt8,
                                                 f8* __restrict__ Lraw8,
                                                 float* __restrict__ Lmax) {
    __shared__ float smax[4];
    __shared__ float scoef[Cv];
    if (threadIdx.x < Cv) {               // lanes 0..31 of wave 0
        int c = threadIdx.x;
        float e = EXP2R(W[c] * LOG2E);
        float wsum = e;
#pragma unroll
        for (int off = 16; off > 0; off >>= 1)
            wsum += __shfl_xor(wsum, off, 64);   // stays within lanes 0..31
        scoef[c] = e / (wsum * fmaxf(Mc[c], 1.0f));
    }
    __syncthreads();

    int tid = blockIdx.x * 256 + threadIdx.x;     // 0 .. B*G/8-1
    float h[8];
#pragma unroll
    for (int e = 0; e < 8; ++e) h[e] = 0.0f;
#pragma unroll
    for (int c = 0; c < Cv; ++c) {
        float w = scoef[c];                        // LDS broadcast
        h8 v = Csh8[(size_t)c * (Gv * 8) + tid];
#pragma unroll
        for (int j = 0; j < 4; ++j) {
            h[2 * j]     = fmaf(w, __low2float(v.h[j]),  h[2 * j]);
            h[2 * j + 1] = fmaf(w, __high2float(v.h[j]), h[2 * j + 1]);
        }
    }

    f8 r = Rt8[tid];
    const float* rp = &r.a.x;
    f8 outv;
    float* op = &outv.a.x;
    float vmax = 0.0f;
#pragma unroll
    for (int e = 0; e < 8; ++e) {
        float hn = h[e];                  // hden == 1
        float rv = rp[e];
        float mx = fmaxf(rv, hn), mn = fminf(rv, hn);
        float t  = EXP2R((mn - mx) * RLOG2E_G);
        float ls = fmaf(GAMMA * LN2, LOG2R(1.0f + t), mx);
        op[e] = ls;
        vmax = fmaxf(vmax, ls);
    }
    Lraw8[tid] = outv;
    block_atomic_max(vmax, Lmax, smax);
}

// R = Lraw / max(Lmax,1); non-last steps refresh Rt (f32) + Rth (fp16);
// last step writes output in [B,G] layout.  float4 (4 consecutive b, one g).
__global__ __launch_bounds__(256) void k_norm(const float4* __restrict__ Lraw4,
                                              const float* __restrict__ Lmax,
                                              float4* __restrict__ Rt4,
                                              __half2* __restrict__ Rth2,
                                              float* __restrict__ out,
                                              int last) {
    int tid = blockIdx.x * 256 + threadIdx.x;     // 0 .. B*G/4-1
    float d = fmaxf(Lmax[0], 1.0f);
    float4 lv = Lraw4[tid];
    float4 v;
    v.x = lv.x / d; v.y = lv.y / d; v.z = lv.z / d; v.w = lv.w / d;
    if (last) {
        int lin = tid * 4;
        int g = lin >> 6, b = lin & 63;           // 4 consecutive b, same g
        out[(b + 0) * Gv + g] = v.x;
        out[(b + 1) * Gv + g] = v.y;
        out[(b + 2) * Gv + g] = v.z;
        out[(b + 3) * Gv + g] = v.w;
    } else {
        Rt4[tid] = v;
        Rth2[2 * tid]     = __floats2half2_rn(v.x, v.y);
        Rth2[2 * tid + 1] = __floats2half2_rn(v.z, v.w);
    }
}

extern "C" void kernel_launch(void* const* d_in, const int* in_sizes, int n_in,
                              void* d_out, int out_size, void* d_ws, size_t ws_size,
                              hipStream_t stream) {
    const float* x = (const float*)d_in[0];   // [64, 4096]
    const float* W = (const float*)d_in[1];   // [1, 32]
    const int*   I = (const int*)d_in[2];     // [32, 4096, 16, 4]
    float* out = (float*)d_out;               // [64, 4096]

    float*  ws   = (float*)d_ws;
    float*  Rt   = ws;                         // 262144 floats  [G,B] f32
    float*  Lraw = ws + 262144;                // 262144
    float*  maxb = ws + 524288;                // 4 * 64 floats (atomic slots)
    __half* Rth  = (__half*)(ws + 524544);     // 262144 halves [G,B] fp16
    __half* Csh  = (__half*)(ws + 1048576);    // 8388608 halves (16 MB)

    (void)hipMemsetAsync(maxb, 0, NSTEP * 64 * sizeof(float), stream);
    k_transpose<<<Gv / 64, 256, 0, stream>>>(x, Rt, (__half2*)Rth);

    for (int step = 0; step < NSTEP; ++step) {
        float* Mc = maxb + step * 64;     // [32] per-clause maxima
        float* Lm = Mc + 33;
        k_clauses<<<(Cv * Gv) / 32, 256, 0, stream>>>((const h8*)Rth, (const int4*)I,
                                                      (h8*)Csh, Mc);
        k_combupd<<<(Bv * Gv) / 2048, 256, 0, stream>>>((const h8*)Csh, W, Mc,
                                                        (const f8*)Rt, (f8*)Lraw, Lm);
        k_norm   <<<(Bv * Gv) / 1024, 256, 0, stream>>>((const float4*)Lraw, Lm,
                                                        (float4*)Rt, (__half2*)Rth,
                                                        out, step == NSTEP - 1);
    }
}

// Round 11
// 180.675 us; speedup vs baseline: 3.2705x; 1.4936x over previous
//
#include <hip/hip_runtime.h>
#include <hip/hip_fp16.h>

#define Bv 64
#define Gv 4096
#define Cv 32
#define Sv 16
#define NSTEP 4
#define LOG2E 1.4426950408889634f
#define LN2   0.6931471805599453f
#define GAMMA 0.01f
#define RLOG2E_G 144.26950408889634f        // LOG2E / GAMMA
#define SHIFT    72.0f                       // fixed LSE shift
#define UNSHIFT  0.4990659758388636f         // GAMMA * LN2 * 72

// raw HW transcendentals (v_exp_f32 / v_log_f32, base-2). exp2 arg in [-72, 72.3]
// -> no over/underflow; log2 arg > 0 always (sum >= 16*2^-72).
#define EXP2R(x) __builtin_amdgcn_exp2f(x)
#define LOG2R(x) __builtin_amdgcn_logf(x)

struct __align__(16) h8 { __half2 h[4]; };   // 8 fp16, one dwordx4
struct __align__(16) f8 { float4 a, b; };    // 8 f32

__device__ __forceinline__ float wave_max(float v) {
#pragma unroll
    for (int off = 32; off > 0; off >>= 1)
        v = fmaxf(v, __shfl_xor(v, off, 64));
    return v;
}

// ---- one-time: I [c][g][s] int4 -> packed pre-scaled byte offsets ----
// I_tp layout: [c][gc 0..63][s 0..15][lane 0..63] uint2, fields = idx*16 (16-bit).
__global__ __launch_bounds__(256) void k_itrans(const int4* __restrict__ I4,
                                                uint2* __restrict__ IT) {
    __shared__ int4 lds[64 * 17];
    int blk = blockIdx.x;                 // 32 c * 64 gc
    int c = blk >> 6, gc = blk & 63;
    size_t base = ((size_t)c * Gv + gc * 64) * Sv;   // int4 elems, [g][s] order
#pragma unroll
    for (int i = 0; i < 4; ++i) {
        int e = threadIdx.x + i * 256;    // e = gi*16 + s
        int4 ii = I4[base + e];
        lds[(e >> 4) * 17 + (e & 15)] = ii;
    }
    __syncthreads();
    size_t obase = (size_t)(c * 64 + gc) * 1024;
#pragma unroll
    for (int i = 0; i < 4; ++i) {
        int o = threadIdx.x + i * 256;    // o = s*64 + gi
        int4 ii = lds[(o & 63) * 17 + (o >> 6)];
        uint2 p;
        p.x = ((unsigned)ii.x << 4) | ((unsigned)ii.y << 20);
        p.y = ((unsigned)ii.z << 4) | ((unsigned)ii.w << 20);
        IT[obase + o] = p;
    }
}

// x [B,G] -> Rt (f32) and Rth (fp16), both OCT-MAJOR: elem(b,g) at
// oct*G*8 + g*8 + (b&7), oct = b>>3.  (h8/f8 index = oct*G + g)
__global__ __launch_bounds__(256) void k_transpose(const float* __restrict__ x,
                                                   f8* __restrict__ Rt8,
                                                   h8* __restrict__ Rth8) {
    __shared__ float tile[64][65];
    int g0 = blockIdx.x * 64;
#pragma unroll
    for (int i = 0; i < 16; ++i) {
        int t = threadIdx.x + i * 256;
        int b = t >> 6, gi = t & 63;
        tile[gi][b] = x[b * Gv + g0 + gi];
    }
    __syncthreads();
#pragma unroll
    for (int e = 0; e < 2; ++e) {
        int idx = threadIdx.x + e * 256;  // 512 = 64 gi * 8 oct
        int gi = idx & 63, oct = idx >> 6;
        float v[8];
#pragma unroll
        for (int k = 0; k < 8; ++k) v[k] = tile[gi][oct * 8 + k];
        f8 fv;
        fv.a = make_float4(v[0], v[1], v[2], v[3]);
        fv.b = make_float4(v[4], v[5], v[6], v[7]);
        Rt8[oct * Gv + g0 + gi] = fv;
        h8 hv;
#pragma unroll
        for (int j = 0; j < 4; ++j) hv.h[j] = __floats2half2_rn(v[2 * j], v[2 * j + 1]);
        Rth8[oct * Gv + g0 + gi] = hv;
    }
}

// block = (c, oct, ghalf). LDS-staged gather: table = full G x 8-batch fp16
// slice (64 KB). All S*L gathers hit LDS (ds_read_b128, pre-scaled offsets).
__global__ __launch_bounds__(512, 4)
void k_clauses(const h8* __restrict__ Rth8, const uint2* __restrict__ IT,
               h8* __restrict__ Csh8, float* __restrict__ Mc) {
    __shared__ h8 tbl[Gv];                // 64 KB
    __shared__ float smax[8];
    int tid = threadIdx.x;
    int blk = blockIdx.x;                 // 512: c(5)|oct(3)|ghalf(1)
    int c    = blk >> 4;
    int oct  = (blk >> 1) & 7;
    int ghalf = blk & 1;

    const h8* __restrict__ src = Rth8 + (size_t)oct * Gv;
#pragma unroll
    for (int i = 0; i < 8; ++i) tbl[tid + i * 512] = src[tid + i * 512];
    __syncthreads();

    int lane = tid & 63, wid = tid >> 6;
    const char* tb = (const char*)tbl;
    float vmax = 0.0f;

#pragma unroll
    for (int iter = 0; iter < 4; ++iter) {
        int gc = ghalf * 32 + wid * 4 + iter;
        const uint2* __restrict__ Ig = IT + (size_t)(c * 64 + gc) * 1024 + lane;

        float sum[8];
#pragma unroll
        for (int e = 0; e < 8; ++e) sum[e] = 0.0f;

#pragma unroll
        for (int s = 0; s < Sv; ++s) {
            uint2 u = Ig[s * 64];
            unsigned a0 = u.x & 0xFFFFu, a1 = u.x >> 16;
            unsigned a2 = u.y & 0xFFFFu, a3 = u.y >> 16;
            h8 A = *(const h8*)(tb + a0);
            h8 B = *(const h8*)(tb + a1);
            h8 E = *(const h8*)(tb + a2);
            h8 D = *(const h8*)(tb + a3);
#pragma unroll
            for (int j = 0; j < 4; ++j) {
                __half2 q = __hmul2(__hmul2(A.h[j], B.h[j]), __hmul2(E.h[j], D.h[j]));
                sum[2 * j]     += EXP2R(fmaf(__low2float(q),  RLOG2E_G, -SHIFT));
                sum[2 * j + 1] += EXP2R(fmaf(__high2float(q), RLOG2E_G, -SHIFT));
            }
        }

        float ls[8];
#pragma unroll
        for (int e = 0; e < 8; ++e)
            ls[e] = fmaf(GAMMA * LN2, LOG2R(sum[e]), UNSHIFT);

        h8 outv;
#pragma unroll
        for (int j = 0; j < 4; ++j)
            outv.h[j] = __floats2half2_rn(ls[2 * j], ls[2 * j + 1]);
        Csh8[((size_t)c * 8 + oct) * Gv + gc * 64 + lane] = outv;

#pragma unroll
        for (int e = 0; e < 8; ++e) vmax = fmaxf(vmax, ls[e]);
    }

    vmax = wave_max(vmax);
    if (lane == 0) smax[wid] = vmax;
    __syncthreads();
    if (tid == 0) {
        float m = smax[0];
#pragma unroll
        for (int i = 1; i < 8; ++i) m = fmaxf(m, smax[i]);
        atomicMax((int*)(Mc + c), __float_as_int(m));   // c uniform across block
    }
}

// Fused combine+update (hden == 1: H is a convex combination of values <= 1).
// All buffers oct-major; tid = oct*Gv + g.  8 elems per thread.
__global__ __launch_bounds__(256) void k_combupd(const h8* __restrict__ Csh8,
                                                 const float* __restrict__ W,
                                                 const float* __restrict__ Mc,
                                                 const f8* __restrict__ Rt8,
                                                 f8* __restrict__ Lraw8,
                                                 float* __restrict__ Lmax) {
    __shared__ float smax[4];
    __shared__ float scoef[Cv];
    if (threadIdx.x < Cv) {               // lanes 0..31 of wave 0
        int c = threadIdx.x;
        float e = EXP2R(W[c] * LOG2E);
        float wsum = e;
#pragma unroll
        for (int off = 16; off > 0; off >>= 1)
            wsum += __shfl_xor(wsum, off, 64);
        scoef[c] = e / (wsum * fmaxf(Mc[c], 1.0f));
    }
    __syncthreads();

    int tid = blockIdx.x * 256 + threadIdx.x;     // 0 .. B*G/8-1
    float h[8];
#pragma unroll
    for (int e = 0; e < 8; ++e) h[e] = 0.0f;
#pragma unroll
    for (int c = 0; c < Cv; ++c) {
        float w = scoef[c];
        h8 v = Csh8[(size_t)c * (Gv * 8) + tid];
#pragma unroll
        for (int j = 0; j < 4; ++j) {
            h[2 * j]     = fmaf(w, __low2float(v.h[j]),  h[2 * j]);
            h[2 * j + 1] = fmaf(w, __high2float(v.h[j]), h[2 * j + 1]);
        }
    }

    f8 r = Rt8[tid];
    const float* rp = &r.a.x;
    f8 outv;
    float* op = &outv.a.x;
    float vmax = 0.0f;
#pragma unroll
    for (int e = 0; e < 8; ++e) {
        float hn = h[e];                  // hden == 1
        float rv = rp[e];
        float mx = fmaxf(rv, hn), mn = fminf(rv, hn);
        float t  = EXP2R((mn - mx) * RLOG2E_G);
        float ls = fmaf(GAMMA * LN2, LOG2R(1.0f + t), mx);
        op[e] = ls;
        vmax = fmaxf(vmax, ls);
    }
    Lraw8[tid] = outv;
    {
        vmax = wave_max(vmax);
        int lane = threadIdx.x & 63, wid = threadIdx.x >> 6;
        if (lane == 0) smax[wid] = vmax;
        __syncthreads();
        if (threadIdx.x == 0) {
            float m = fmaxf(fmaxf(smax[0], smax[1]), fmaxf(smax[2], smax[3]));
            atomicMax((int*)Lmax, __float_as_int(m));
        }
    }
}

// R = Lraw / max(Lmax,1), oct-major float4; last step scatters to out [B,G].
__global__ __launch_bounds__(256) void k_norm(const float4* __restrict__ Lraw4,
                                              const float* __restrict__ Lmax,
                                              float4* __restrict__ Rt4,
                                              __half2* __restrict__ Rth2,
                                              float* __restrict__ out,
                                              int last) {
    int tid = blockIdx.x * 256 + threadIdx.x;     // 0 .. B*G/4-1
    float d = fmaxf(Lmax[0], 1.0f);
    float4 lv = Lraw4[tid];
    float4 v;
    v.x = lv.x / d; v.y = lv.y / d; v.z = lv.z / d; v.w = lv.w / d;
    if (last) {
        int lin = tid * 4;                        // oct-major linear f32 index
        int oct = lin >> 15;
        int g   = (lin >> 3) & (Gv - 1);
        int k0  = lin & 7;                        // 0 or 4
        int b   = oct * 8 + k0;
        out[(b + 0) * Gv + g] = v.x;
        out[(b + 1) * Gv + g] = v.y;
        out[(b + 2) * Gv + g] = v.z;
        out[(b + 3) * Gv + g] = v.w;
    } else {
        Rt4[tid] = v;
        Rth2[2 * tid]     = __floats2half2_rn(v.x, v.y);
        Rth2[2 * tid + 1] = __floats2half2_rn(v.z, v.w);
    }
}

extern "C" void kernel_launch(void* const* d_in, const int* in_sizes, int n_in,
                              void* d_out, int out_size, void* d_ws, size_t ws_size,
                              hipStream_t stream) {
    const float* x = (const float*)d_in[0];   // [64, 4096]
    const float* W = (const float*)d_in[1];   // [1, 32]
    const int*   I = (const int*)d_in[2];     // [32, 4096, 16, 4]
    float* out = (float*)d_out;               // [64, 4096]

    float*  ws   = (float*)d_ws;
    float*  Rt   = ws;                         // 262144 f32, oct-major
    float*  Lraw = ws + 262144;                // 262144 f32, oct-major
    float*  maxb = ws + 524288;                // NSTEP*64 atomic slots
    __half* Rth  = (__half*)(ws + 524544);     // 262144 fp16, oct-major
    __half* Csh  = (__half*)(ws + 1048576);    // 8388608 fp16 (16 MB)
    uint2*  ITp  = (uint2*) (ws + 5242880);    // 2097152 uint2 (16 MB)
                                               // total 9437184 floats = 36 MB

    (void)hipMemsetAsync(maxb, 0, NSTEP * 64 * sizeof(float), stream);
    k_itrans   <<<Cv * 64, 256, 0, stream>>>((const int4*)I, ITp);
    k_transpose<<<Gv / 64, 256, 0, stream>>>(x, (f8*)Rt, (h8*)Rth);

    for (int step = 0; step < NSTEP; ++step) {
        float* Mc = maxb + step * 64;     // [32] per-clause maxima
        float* Lm = Mc + 33;
        k_clauses<<<512, 512, 0, stream>>>((const h8*)Rth, (const uint2*)ITp,
                                           (h8*)Csh, Mc);
        k_combupd<<<(Bv * Gv) / 2048, 256, 0, stream>>>((const h8*)Csh, W, Mc,
                                                        (const f8*)Rt, (f8*)Lraw, Lm);
        k_norm   <<<(Bv * Gv) / 1024, 256, 0, stream>>>((const float4*)Lraw, Lm,
                                                        (float4*)Rt, (__half2*)Rth,
                                                        out, step == NSTEP - 1);
    }
}

// Round 12
// 175.159 us; speedup vs baseline: 3.3735x; 1.0315x over previous
//
#include <hip/hip_runtime.h>
#include <hip/hip_fp16.h>

#define Bv 64
#define Gv 4096
#define Cv 32
#define Sv 16
#define NSTEP 4
#define LOG2E 1.4426950408889634f
#define LN2   0.6931471805599453f
#define GAMMA 0.01f
#define RLOG2E_G 144.26950408889634f        // LOG2E / GAMMA
#define SHIFT    72.0f                       // fixed LSE shift
#define UNSHIFT  0.4990659758388636f         // GAMMA * LN2 * 72

// raw HW transcendentals (v_exp_f32 / v_log_f32, base-2). exp2 arg in [-72, 72.3]
// -> no over/underflow; log2 arg > 0 always (sum >= 16*2^-72).
#define EXP2R(x) __builtin_amdgcn_exp2f(x)
#define LOG2R(x) __builtin_amdgcn_logf(x)

struct __align__(16) h8 { __half2 h[4]; };   // 8 fp16, one dwordx4
struct __align__(16) f8 { float4 a, b; };    // 8 f32

__device__ __forceinline__ float wave_max(float v) {
#pragma unroll
    for (int off = 32; off > 0; off >>= 1)
        v = fmaxf(v, __shfl_xor(v, off, 64));
    return v;
}

// ---- one-time: I [c][g][s] int4 -> packed pre-scaled byte offsets ----
// IT layout: [c][gc 0..63][s 0..15][lane 0..63] uint2, fields = idx*16 (16-bit).
__global__ __launch_bounds__(256) void k_itrans(const int4* __restrict__ I4,
                                                uint2* __restrict__ IT) {
    __shared__ int4 lds[64 * 17];
    int blk = blockIdx.x;                 // 32 c * 64 gc
    int c = blk >> 6, gc = blk & 63;
    size_t base = ((size_t)c * Gv + gc * 64) * Sv;   // int4 elems, [g][s] order
#pragma unroll
    for (int i = 0; i < 4; ++i) {
        int e = threadIdx.x + i * 256;    // e = gi*16 + s
        int4 ii = I4[base + e];
        lds[(e >> 4) * 17 + (e & 15)] = ii;
    }
    __syncthreads();
    size_t obase = (size_t)(c * 64 + gc) * 1024;
#pragma unroll
    for (int i = 0; i < 4; ++i) {
        int o = threadIdx.x + i * 256;    // o = s*64 + gi
        int4 ii = lds[(o & 63) * 17 + (o >> 6)];
        uint2 p;
        p.x = ((unsigned)ii.x << 4) | ((unsigned)ii.y << 20);
        p.y = ((unsigned)ii.z << 4) | ((unsigned)ii.w << 20);
        IT[obase + o] = p;
    }
}

// x [B,G] -> Lraw0 (f32) OCT-MAJOR: f8 index = oct*Gv + g  (oct = b>>3)
__global__ __launch_bounds__(256) void k_transpose(const float* __restrict__ x,
                                                   f8* __restrict__ L8) {
    __shared__ float tile[64][65];
    int g0 = blockIdx.x * 64;
#pragma unroll
    for (int i = 0; i < 16; ++i) {
        int t = threadIdx.x + i * 256;
        int b = t >> 6, gi = t & 63;
        tile[gi][b] = x[b * Gv + g0 + gi];
    }
    __syncthreads();
#pragma unroll
    for (int e = 0; e < 2; ++e) {
        int idx = threadIdx.x + e * 256;  // 512 = 64 gi * 8 oct
        int gi = idx & 63, oct = idx >> 6;
        f8 fv;
        fv.a = make_float4(tile[gi][oct * 8 + 0], tile[gi][oct * 8 + 1],
                           tile[gi][oct * 8 + 2], tile[gi][oct * 8 + 3]);
        fv.b = make_float4(tile[gi][oct * 8 + 4], tile[gi][oct * 8 + 5],
                           tile[gi][oct * 8 + 6], tile[gi][oct * 8 + 7]);
        L8[oct * Gv + g0 + gi] = fv;
    }
}

// block = (c, oct, ghalf). Stages the full-G 8-batch slice of R =
// Lprev/max(LmPrev,1) into LDS as fp16 (normalize fused into staging);
// all S*L gathers then hit LDS (ds_read_b128, pre-scaled packed offsets).
__global__ __launch_bounds__(512, 4)
void k_clauses(const f8* __restrict__ Lprev, const float* __restrict__ LmPrev,
               const uint2* __restrict__ IT, h8* __restrict__ Csh8,
               float* __restrict__ Mc) {
    __shared__ h8 tbl[Gv];                // 64 KB
    __shared__ float smax[8];
    int tid = threadIdx.x;
    int blk = blockIdx.x;                 // 512: c(5)|oct(3)|ghalf(1)
    int c    = blk >> 4;
    int oct  = (blk >> 1) & 7;
    int ghalf = blk & 1;

    float rd = 1.0f / fmaxf(LmPrev[0], 1.0f);
    const f8* __restrict__ src = Lprev + (size_t)oct * Gv;
#pragma unroll
    for (int i = 0; i < 8; ++i) {
        f8 v = src[tid + i * 512];
        h8 hv;
        hv.h[0] = __floats2half2_rn(v.a.x * rd, v.a.y * rd);
        hv.h[1] = __floats2half2_rn(v.a.z * rd, v.a.w * rd);
        hv.h[2] = __floats2half2_rn(v.b.x * rd, v.b.y * rd);
        hv.h[3] = __floats2half2_rn(v.b.z * rd, v.b.w * rd);
        tbl[tid + i * 512] = hv;
    }
    __syncthreads();

    int lane = tid & 63, wid = tid >> 6;
    const char* tb = (const char*)tbl;
    float vmax = 0.0f;

#pragma unroll
    for (int iter = 0; iter < 4; ++iter) {
        int gc = ghalf * 32 + wid * 4 + iter;
        const uint2* __restrict__ Ig = IT + (size_t)(c * 64 + gc) * 1024 + lane;

        float sum[8];
#pragma unroll
        for (int e = 0; e < 8; ++e) sum[e] = 0.0f;

#pragma unroll
        for (int s = 0; s < Sv; ++s) {
            uint2 u = Ig[s * 64];
            unsigned a0 = u.x & 0xFFFFu, a1 = u.x >> 16;
            unsigned a2 = u.y & 0xFFFFu, a3 = u.y >> 16;
            h8 A = *(const h8*)(tb + a0);
            h8 B = *(const h8*)(tb + a1);
            h8 E = *(const h8*)(tb + a2);
            h8 D = *(const h8*)(tb + a3);
#pragma unroll
            for (int j = 0; j < 4; ++j) {
                __half2 q = __hmul2(__hmul2(A.h[j], B.h[j]), __hmul2(E.h[j], D.h[j]));
                sum[2 * j]     += EXP2R(fmaf(__low2float(q),  RLOG2E_G, -SHIFT));
                sum[2 * j + 1] += EXP2R(fmaf(__high2float(q), RLOG2E_G, -SHIFT));
            }
        }

        float ls[8];
#pragma unroll
        for (int e = 0; e < 8; ++e)
            ls[e] = fmaf(GAMMA * LN2, LOG2R(sum[e]), UNSHIFT);

        h8 outv;
#pragma unroll
        for (int j = 0; j < 4; ++j)
            outv.h[j] = __floats2half2_rn(ls[2 * j], ls[2 * j + 1]);
        Csh8[((size_t)c * 8 + oct) * Gv + gc * 64 + lane] = outv;

#pragma unroll
        for (int e = 0; e < 8; ++e) vmax = fmaxf(vmax, ls[e]);
    }

    vmax = wave_max(vmax);
    if (lane == 0) smax[wid] = vmax;
    __syncthreads();
    if (tid == 0) {
        float m = smax[0];
#pragma unroll
        for (int i = 1; i < 8; ++i) m = fmaxf(m, smax[i]);
        atomicMax((int*)(Mc + c), __float_as_int(m));   // c uniform across block
    }
}

// Fused combine+update (hden == 1: H is a convex combination of values <= 1).
// r = Lprev*1/max(LmPrev,1) inline (deferred normalization).
// Writes UNNORMALIZED Lout + its global max LmOut.  8 elems per thread.
__global__ __launch_bounds__(256) void k_combupd(const h8* __restrict__ Csh8,
                                                 const float* __restrict__ W,
                                                 const float* __restrict__ Mc,
                                                 const f8* __restrict__ Lprev,
                                                 const float* __restrict__ LmPrev,
                                                 f8* __restrict__ Lout,
                                                 float* __restrict__ LmOut) {
    __shared__ float smax[4];
    __shared__ float scoef[Cv];
    if (threadIdx.x < Cv) {               // lanes 0..31 of wave 0
        int c = threadIdx.x;
        float e = EXP2R(W[c] * LOG2E);
        float wsum = e;
#pragma unroll
        for (int off = 16; off > 0; off >>= 1)
            wsum += __shfl_xor(wsum, off, 64);
        scoef[c] = e / (wsum * fmaxf(Mc[c], 1.0f));
    }
    __syncthreads();

    int tid = blockIdx.x * 256 + threadIdx.x;     // 0 .. B*G/8-1
    float h[8];
#pragma unroll
    for (int e = 0; e < 8; ++e) h[e] = 0.0f;
#pragma unroll
    for (int c = 0; c < Cv; ++c) {
        float w = scoef[c];
        h8 v = Csh8[(size_t)c * (Gv * 8) + tid];
#pragma unroll
        for (int j = 0; j < 4; ++j) {
            h[2 * j]     = fmaf(w, __low2float(v.h[j]),  h[2 * j]);
            h[2 * j + 1] = fmaf(w, __high2float(v.h[j]), h[2 * j + 1]);
        }
    }

    float rd = 1.0f / fmaxf(LmPrev[0], 1.0f);
    f8 r = Lprev[tid];
    const float* rp = &r.a.x;
    f8 outv;
    float* op = &outv.a.x;
    float vmax = 0.0f;
#pragma unroll
    for (int e = 0; e < 8; ++e) {
        float hn = h[e];                  // hden == 1
        float rv = rp[e] * rd;            // deferred normalization
        float mx = fmaxf(rv, hn), mn = fminf(rv, hn);
        float t  = EXP2R((mn - mx) * RLOG2E_G);
        float ls = fmaf(GAMMA * LN2, LOG2R(1.0f + t), mx);
        op[e] = ls;
        vmax = fmaxf(vmax, ls);
    }
    Lout[tid] = outv;
    vmax = wave_max(vmax);
    int lane = threadIdx.x & 63, wid = threadIdx.x >> 6;
    if (lane == 0) smax[wid] = vmax;
    __syncthreads();
    if (threadIdx.x == 0) {
        float m = fmaxf(fmaxf(smax[0], smax[1]), fmaxf(smax[2], smax[3]));
        atomicMax((int*)LmOut, __float_as_int(m));
    }
}

// Final: out[b][g] = Lraw/max(Lm,1) scattered from oct-major to [B,G].
__global__ __launch_bounds__(256) void k_out(const float4* __restrict__ Lraw4,
                                             const float* __restrict__ Lm,
                                             float* __restrict__ out) {
    int tid = blockIdx.x * 256 + threadIdx.x;     // 0 .. B*G/4-1
    float d = fmaxf(Lm[0], 1.0f);
    float4 lv = Lraw4[tid];
    int lin = tid * 4;                        // oct-major linear f32 index
    int oct = lin >> 15;
    int g   = (lin >> 3) & (Gv - 1);
    int k0  = lin & 7;                        // 0 or 4
    int b   = oct * 8 + k0;
    out[(b + 0) * Gv + g] = lv.x / d;
    out[(b + 1) * Gv + g] = lv.y / d;
    out[(b + 2) * Gv + g] = lv.z / d;
    out[(b + 3) * Gv + g] = lv.w / d;
}

extern "C" void kernel_launch(void* const* d_in, const int* in_sizes, int n_in,
                              void* d_out, int out_size, void* d_ws, size_t ws_size,
                              hipStream_t stream) {
    const float* x = (const float*)d_in[0];   // [64, 4096]
    const float* W = (const float*)d_in[1];   // [1, 32]
    const int*   I = (const int*)d_in[2];     // [32, 4096, 16, 4]
    float* out = (float*)d_out;               // [64, 4096]

    float*  ws    = (float*)d_ws;
    f8*     LrawA = (f8*)ws;                   // 262144 f32, oct-major
    f8*     LrawB = (f8*)(ws + 262144);        // 262144 f32, oct-major
    float*  maxb  = ws + 524288;               // NSTEP*64 + 64 atomic slots
    __half* Csh   = (__half*)(ws + 1048576);   // 8388608 fp16 (16 MB)
    uint2*  ITp   = (uint2*) (ws + 5242880);   // 2097152 uint2 (16 MB)

    (void)hipMemsetAsync(maxb, 0, (NSTEP * 64 + 64) * sizeof(float), stream);
    k_itrans   <<<Cv * 64, 256, 0, stream>>>((const int4*)I, ITp);
    k_transpose<<<Gv / 64, 256, 0, stream>>>(x, LrawA);

    const float* LmPrev = maxb + NSTEP * 64;   // zeros -> d = 1
    f8* prev = LrawA;
    f8* cur  = LrawB;
    for (int step = 0; step < NSTEP; ++step) {
        float* Mc = maxb + step * 64;     // [32] per-clause maxima
        float* Lm = Mc + 32;
        k_clauses<<<512, 512, 0, stream>>>(prev, LmPrev, (const uint2*)ITp,
                                           (h8*)Csh, Mc);
        k_combupd<<<(Bv * Gv) / 2048, 256, 0, stream>>>((const h8*)Csh, W, Mc,
                                                        prev, LmPrev, cur, Lm);
        LmPrev = Lm;
        f8* t = prev; prev = cur; cur = t;
    }
    k_out<<<(Bv * Gv) / 1024, 256, 0, stream>>>((const float4*)prev, LmPrev, out);
}

// Round 13
// 171.540 us; speedup vs baseline: 3.4446x; 1.0211x over previous
//
#include <hip/hip_runtime.h>
#include <hip/hip_fp16.h>

#define Bv 64
#define Gv 4096
#define Cv 32
#define Sv 16
#define NSTEP 4
#define LOG2E 1.4426950408889634f
#define LN2   0.6931471805599453f
#define GAMMA 0.01f
#define RLOG2E_G 144.26950408889634f        // LOG2E / GAMMA
#define SHIFT    72.0f                       // fixed LSE shift
#define UNSHIFT  0.4990659758388636f         // GAMMA * LN2 * 72

// raw HW transcendentals (v_exp_f32 / v_log_f32, base-2). exp2 arg in [-72, 72.3]
// -> no over/underflow; log2 arg > 0 always (sum >= 16*2^-72).
#define EXP2R(x) __builtin_amdgcn_exp2f(x)
#define LOG2R(x) __builtin_amdgcn_logf(x)

struct __align__(16) h8 { __half2 h[4]; };   // 8 fp16, one dwordx4
struct __align__(16) f8 { float4 a, b; };    // 8 f32

__device__ __forceinline__ float wave_max(float v) {
#pragma unroll
    for (int off = 32; off > 0; off >>= 1)
        v = fmaxf(v, __shfl_xor(v, off, 64));
    return v;
}

// ---- one-time: I [c][g][s] int4 -> packed pre-scaled byte offsets ----
// IT layout: [c][gc 0..63][s 0..15][lane 0..63] uint2, fields = idx*16 (16-bit).
__global__ __launch_bounds__(256) void k_itrans(const int4* __restrict__ I4,
                                                uint2* __restrict__ IT) {
    __shared__ int4 lds[64 * 17];
    int blk = blockIdx.x;                 // 32 c * 64 gc
    int c = blk >> 6, gc = blk & 63;
    size_t base = ((size_t)c * Gv + gc * 64) * Sv;   // int4 elems, [g][s] order
#pragma unroll
    for (int i = 0; i < 4; ++i) {
        int e = threadIdx.x + i * 256;    // e = gi*16 + s
        int4 ii = I4[base + e];
        lds[(e >> 4) * 17 + (e & 15)] = ii;
    }
    __syncthreads();
    size_t obase = (size_t)(c * 64 + gc) * 1024;
#pragma unroll
    for (int i = 0; i < 4; ++i) {
        int o = threadIdx.x + i * 256;    // o = s*64 + gi
        int4 ii = lds[(o & 63) * 17 + (o >> 6)];
        uint2 p;
        p.x = ((unsigned)ii.x << 4) | ((unsigned)ii.y << 20);
        p.y = ((unsigned)ii.z << 4) | ((unsigned)ii.w << 20);
        IT[obase + o] = p;
    }
}

// x [B,G] -> Lraw0 (f32) OCT-MAJOR: f8 index = oct*Gv + g  (oct = b>>3)
__global__ __launch_bounds__(256) void k_transpose(const float* __restrict__ x,
                                                   f8* __restrict__ L8) {
    __shared__ float tile[64][65];
    int g0 = blockIdx.x * 64;
#pragma unroll
    for (int i = 0; i < 16; ++i) {
        int t = threadIdx.x + i * 256;
        int b = t >> 6, gi = t & 63;
        tile[gi][b] = x[b * Gv + g0 + gi];
    }
    __syncthreads();
#pragma unroll
    for (int e = 0; e < 2; ++e) {
        int idx = threadIdx.x + e * 256;  // 512 = 64 gi * 8 oct
        int gi = idx & 63, oct = idx >> 6;
        f8 fv;
        fv.a = make_float4(tile[gi][oct * 8 + 0], tile[gi][oct * 8 + 1],
                           tile[gi][oct * 8 + 2], tile[gi][oct * 8 + 3]);
        fv.b = make_float4(tile[gi][oct * 8 + 4], tile[gi][oct * 8 + 5],
                           tile[gi][oct * 8 + 6], tile[gi][oct * 8 + 7]);
        L8[oct * Gv + g0 + gi] = fv;
    }
}

// block = (c, oct, ghalf), 1024 threads (16 waves x 2 gc-iters).
// 2 blocks/CU -> 2048 thr/CU = 8 waves/SIMD (max occupancy), LDS 2x64 = 128 KB.
// Stages full-G 8-batch slice of R = Lprev/max(LmPrev,1) into LDS as fp16;
// all S*L gathers hit LDS (ds_read_b128, pre-scaled packed offsets).
__global__ __attribute__((amdgpu_flat_work_group_size(1024, 1024),
                          amdgpu_waves_per_eu(8, 8)))
void k_clauses(const f8* __restrict__ Lprev, const float* __restrict__ LmPrev,
               const uint2* __restrict__ IT, h8* __restrict__ Csh8,
               float* __restrict__ Mc) {
    __shared__ h8 tbl[Gv];                // 64 KB
    __shared__ float smax[16];
    int tid = threadIdx.x;
    int blk = blockIdx.x;                 // 512: c(5)|oct(3)|ghalf(1)
    int c    = blk >> 4;
    int oct  = (blk >> 1) & 7;
    int ghalf = blk & 1;

    float rd = 1.0f / fmaxf(LmPrev[0], 1.0f);
    const f8* __restrict__ src = Lprev + (size_t)oct * Gv;
#pragma unroll
    for (int i = 0; i < 4; ++i) {
        f8 v = src[tid + i * 1024];
        h8 hv;
        hv.h[0] = __floats2half2_rn(v.a.x * rd, v.a.y * rd);
        hv.h[1] = __floats2half2_rn(v.a.z * rd, v.a.w * rd);
        hv.h[2] = __floats2half2_rn(v.b.x * rd, v.b.y * rd);
        hv.h[3] = __floats2half2_rn(v.b.z * rd, v.b.w * rd);
        tbl[tid + i * 1024] = hv;
    }
    __syncthreads();

    int lane = tid & 63, wid = tid >> 6;  // wid 0..15
    const char* tb = (const char*)tbl;
    float vmax = 0.0f;

#pragma unroll
    for (int iter = 0; iter < 2; ++iter) {
        int gc = ghalf * 32 + wid * 2 + iter;
        const uint2* __restrict__ Ig = IT + (size_t)(c * 64 + gc) * 1024 + lane;

        float sum[8];
#pragma unroll
        for (int e = 0; e < 8; ++e) sum[e] = 0.0f;

#pragma unroll
        for (int s = 0; s < Sv; ++s) {
            uint2 u = Ig[s * 64];
            unsigned a0 = u.x & 0xFFFFu, a1 = u.x >> 16;
            unsigned a2 = u.y & 0xFFFFu, a3 = u.y >> 16;
            h8 A = *(const h8*)(tb + a0);
            h8 B = *(const h8*)(tb + a1);
            h8 E = *(const h8*)(tb + a2);
            h8 D = *(const h8*)(tb + a3);
#pragma unroll
            for (int j = 0; j < 4; ++j) {
                __half2 q = __hmul2(__hmul2(A.h[j], B.h[j]), __hmul2(E.h[j], D.h[j]));
                sum[2 * j]     += EXP2R(fmaf(__low2float(q),  RLOG2E_G, -SHIFT));
                sum[2 * j + 1] += EXP2R(fmaf(__high2float(q), RLOG2E_G, -SHIFT));
            }
        }

        float ls[8];
#pragma unroll
        for (int e = 0; e < 8; ++e)
            ls[e] = fmaf(GAMMA * LN2, LOG2R(sum[e]), UNSHIFT);

        h8 outv;
#pragma unroll
        for (int j = 0; j < 4; ++j)
            outv.h[j] = __floats2half2_rn(ls[2 * j], ls[2 * j + 1]);
        Csh8[((size_t)c * 8 + oct) * Gv + gc * 64 + lane] = outv;

#pragma unroll
        for (int e = 0; e < 8; ++e) vmax = fmaxf(vmax, ls[e]);
    }

    vmax = wave_max(vmax);
    if (lane == 0) smax[wid] = vmax;
    __syncthreads();
    if (tid == 0) {
        float m = smax[0];
#pragma unroll
        for (int i = 1; i < 16; ++i) m = fmaxf(m, smax[i]);
        atomicMax((int*)(Mc + c), __float_as_int(m));   // c uniform across block
    }
}

// Fused combine+update (hden == 1: H is a convex combination of values <= 1).
// r = Lprev*1/max(LmPrev,1) inline (deferred normalization).
// Writes UNNORMALIZED Lout + its global max LmOut.  8 elems per thread.
__global__ __launch_bounds__(256) void k_combupd(const h8* __restrict__ Csh8,
                                                 const float* __restrict__ W,
                                                 const float* __restrict__ Mc,
                                                 const f8* __restrict__ Lprev,
                                                 const float* __restrict__ LmPrev,
                                                 f8* __restrict__ Lout,
                                                 float* __restrict__ LmOut) {
    __shared__ float smax[4];
    __shared__ float scoef[Cv];
    if (threadIdx.x < Cv) {               // lanes 0..31 of wave 0
        int c = threadIdx.x;
        float e = EXP2R(W[c] * LOG2E);
        float wsum = e;
#pragma unroll
        for (int off = 16; off > 0; off >>= 1)
            wsum += __shfl_xor(wsum, off, 64);
        scoef[c] = e / (wsum * fmaxf(Mc[c], 1.0f));
    }
    __syncthreads();

    int tid = blockIdx.x * 256 + threadIdx.x;     // 0 .. B*G/8-1
    float h[8];
#pragma unroll
    for (int e = 0; e < 8; ++e) h[e] = 0.0f;
#pragma unroll
    for (int c = 0; c < Cv; ++c) {
        float w = scoef[c];
        h8 v = Csh8[(size_t)c * (Gv * 8) + tid];
#pragma unroll
        for (int j = 0; j < 4; ++j) {
            h[2 * j]     = fmaf(w, __low2float(v.h[j]),  h[2 * j]);
            h[2 * j + 1] = fmaf(w, __high2float(v.h[j]), h[2 * j + 1]);
        }
    }

    float rd = 1.0f / fmaxf(LmPrev[0], 1.0f);
    f8 r = Lprev[tid];
    const float* rp = &r.a.x;
    f8 outv;
    float* op = &outv.a.x;
    float vmax = 0.0f;
#pragma unroll
    for (int e = 0; e < 8; ++e) {
        float hn = h[e];                  // hden == 1
        float rv = rp[e] * rd;            // deferred normalization
        float mx = fmaxf(rv, hn), mn = fminf(rv, hn);
        float t  = EXP2R((mn - mx) * RLOG2E_G);
        float ls = fmaf(GAMMA * LN2, LOG2R(1.0f + t), mx);
        op[e] = ls;
        vmax = fmaxf(vmax, ls);
    }
    Lout[tid] = outv;
    vmax = wave_max(vmax);
    int lane = threadIdx.x & 63, wid = threadIdx.x >> 6;
    if (lane == 0) smax[wid] = vmax;
    __syncthreads();
    if (threadIdx.x == 0) {
        float m = fmaxf(fmaxf(smax[0], smax[1]), fmaxf(smax[2], smax[3]));
        atomicMax((int*)LmOut, __float_as_int(m));
    }
}

// Final: out[b][g] = Lraw/max(Lm,1) scattered from oct-major to [B,G].
__global__ __launch_bounds__(256) void k_out(const float4* __restrict__ Lraw4,
                                             const float* __restrict__ Lm,
                                             float* __restrict__ out) {
    int tid = blockIdx.x * 256 + threadIdx.x;     // 0 .. B*G/4-1
    float d = fmaxf(Lm[0], 1.0f);
    float4 lv = Lraw4[tid];
    int lin = tid * 4;                        // oct-major linear f32 index
    int oct = lin >> 15;
    int g   = (lin >> 3) & (Gv - 1);
    int k0  = lin & 7;                        // 0 or 4
    int b   = oct * 8 + k0;
    out[(b + 0) * Gv + g] = lv.x / d;
    out[(b + 1) * Gv + g] = lv.y / d;
    out[(b + 2) * Gv + g] = lv.z / d;
    out[(b + 3) * Gv + g] = lv.w / d;
}

extern "C" void kernel_launch(void* const* d_in, const int* in_sizes, int n_in,
                              void* d_out, int out_size, void* d_ws, size_t ws_size,
                              hipStream_t stream) {
    const float* x = (const float*)d_in[0];   // [64, 4096]
    const float* W = (const float*)d_in[1];   // [1, 32]
    const int*   I = (const int*)d_in[2];     // [32, 4096, 16, 4]
    float* out = (float*)d_out;               // [64, 4096]

    float*  ws    = (float*)d_ws;
    f8*     LrawA = (f8*)ws;                   // 262144 f32, oct-major
    f8*     LrawB = (f8*)(ws + 262144);        // 262144 f32, oct-major
    float*  maxb  = ws + 524288;               // NSTEP*64 + 64 atomic slots
    __half* Csh   = (__half*)(ws + 1048576);   // 8388608 fp16 (16 MB)
    uint2*  ITp   = (uint2*) (ws + 5242880);   // 2097152 uint2 (16 MB)

    (void)hipMemsetAsync(maxb, 0, (NSTEP * 64 + 64) * sizeof(float), stream);
    k_itrans   <<<Cv * 64, 256, 0, stream>>>((const int4*)I, ITp);
    k_transpose<<<Gv / 64, 256, 0, stream>>>(x, LrawA);

    const float* LmPrev = maxb + NSTEP * 64;   // zeros -> d = 1
    f8* prev = LrawA;
    f8* cur  = LrawB;
    for (int step = 0; step < NSTEP; ++step) {
        float* Mc = maxb + step * 64;     // [32] per-clause maxima
        float* Lm = Mc + 32;
        k_clauses<<<512, 1024, 0, stream>>>(prev, LmPrev, (const uint2*)ITp,
                                            (h8*)Csh, Mc);
        k_combupd<<<(Bv * Gv) / 2048, 256, 0, stream>>>((const h8*)Csh, W, Mc,
                                                        prev, LmPrev, cur, Lm);
        LmPrev = Lm;
        f8* t = prev; prev = cur; cur = t;
    }
    k_out<<<(Bv * Gv) / 1024, 256, 0, stream>>>((const float4*)prev, LmPrev, out);
}